// Round 5
// baseline (4965.725 us; speedup 1.0000x reference)
//
#include <hip/hip_runtime.h>

#define SEQL 512
#define BATCH 256
#define EMB 256
#define HID 512
#define NTOT 2048  // 4*HID

typedef __attribute__((ext_vector_type(8))) short bf16x8;
typedef __attribute__((ext_vector_type(4))) float f32x4;
typedef __attribute__((ext_vector_type(4))) unsigned short us4;
typedef unsigned short u16;

// ---------- helpers ----------
static __device__ __forceinline__ u16 f2bf(float f) {
  unsigned u = __float_as_uint(f);
  u += 0x7FFFu + ((u >> 16) & 1u);  // RNE
  return (u16)(u >> 16);
}
static __device__ __forceinline__ float bf2f(u16 s) {
  return __uint_as_float(((unsigned)s) << 16);
}
static __device__ __forceinline__ float sigmoidf_(float z) {
  return 1.f / (1.f + __expf(-z));
}
static __device__ __forceinline__ float tanhf_(float x) {
  float e = __expf(2.f * fabsf(x));
  float t = 1.f - 2.f / (e + 1.f);
  return copysignf(t, x);
}
static __device__ __forceinline__ f32x4 mfma16(bf16x8 a, bf16x8 b, f32x4 c) {
  return __builtin_amdgcn_mfma_f32_16x16x32_bf16(a, b, c, 0, 0, 0);
}
static __device__ __forceinline__ void gld16(const u16* g, u16* l) {
  __builtin_amdgcn_global_load_lds((const __attribute__((address_space(1))) void*)g,
                                   (__attribute__((address_space(3))) void*)l, 16, 0, 0);
}
// ---- round-3-PROVEN device-scope (MALL) ops: sc1 everywhere, no cache maint ----
static __device__ __forceinline__ bf16x8 ldx4_dev(const u16* p) {
  bf16x8 r;
  asm volatile("global_load_dwordx4 %0, %1, off sc1" : "=v"(r) : "v"(p));
  return r;
}
static __device__ __forceinline__ void st2_dev(u16* p, unsigned v) {
  asm volatile("global_store_short %0, %1, off sc1" :: "v"(p), "v"(v) : "memory");
}
static __device__ __forceinline__ void flag_add_dev(unsigned* p) {
  unsigned one = 1u;
  asm volatile("global_atomic_add %0, %1, off sc1" :: "v"(p), "v"(one) : "memory");
}
static __device__ __forceinline__ unsigned flag_poll_dev(const unsigned* p) {
  unsigned v;
  asm volatile("global_load_dword %0, %1, off sc0 sc1\ns_waitcnt vmcnt(0)"
               : "=v"(v) : "v"(p) : "memory");
  return v;
}

// ---------- split f32 -> bf16 hi/lo (Wx once) ----------
__global__ void k_split(const float* __restrict__ src, u16* __restrict__ hi,
                        u16* __restrict__ lo, int n) {
  for (int i = blockIdx.x * blockDim.x + threadIdx.x; i < n;
       i += gridDim.x * blockDim.x) {
    float v = src[i];
    u16 h = f2bf(v);
    hi[i] = h;
    lo[i] = f2bf(v - bf2f(h));
  }
}

// bias2[n] : n = g*512+j ; 2*b for f,i,o ; 1*b for a
__global__ void k_bias2(const float* __restrict__ bf_, const float* __restrict__ bi_,
                        const float* __restrict__ bo_, const float* __restrict__ ba_,
                        float* __restrict__ bias2) {
  int n = blockIdx.x * blockDim.x + threadIdx.x;
  if (n >= NTOT) return;
  int g = n >> 9, j = n & 511;
  const float* p = (g == 0) ? bf_ : (g == 1) ? bi_ : (g == 2) ? bo_ : ba_;
  bias2[n] = ((g < 3) ? 2.f : 1.f) * p[j];
}

// ---------- pack Waa into MFMA B-fragment order (de-dup: indexed by mem only) ----
// fi = ((mem*4 + w)*4 + nf)*8 + kf   (512 frags x 64 lanes x 8 elems = 512KB each)
// lane l: j = mem*128 + (w>>1)*64 + nf*16 + (l&15)
//         k = (w&1)*256 + kf*32 + (l>>4)*8 + e
__global__ void k_packW(const float* __restrict__ Waa, u16* __restrict__ WPhi,
                        u16* __restrict__ WPlo) {
  int idx = blockIdx.x * 256 + threadIdx.x;  // 0 .. 512*64-1
  int lane = idx & 63;
  int fi = idx >> 6;
  if (fi >= 512) return;
  int kf = fi & 7, nf = (fi >> 3) & 3, w = (fi >> 5) & 3, mem = fi >> 7;
  int j = mem * 128 + (w >> 1) * 64 + nf * 16 + (lane & 15);
  int k0 = (w & 1) * 256 + kf * 32 + (lane >> 4) * 8;
  size_t base = (size_t)idx * 8;
#pragma unroll
  for (int e = 0; e < 8; ++e) {
    float v = Waa[(size_t)j * HID + k0 + e];
    u16 h = f2bf(v);
    WPhi[base + e] = h;
    WPlo[base + e] = f2bf(v - bf2f(h));
  }
}

// ---------- chunk GEMM with fused X split ----------
// G2 layout: [tloc][bgrp 16][gate 4][j 512][b 16] f32
__global__ __launch_bounds__(256) void k_gemm(
    const float* __restrict__ X,  // [Mc][256] f32 (chunk base)
    const u16* __restrict__ Bhi, const u16* __restrict__ Blo,
    const float* __restrict__ bias2, float* __restrict__ G2) {
  __shared__ u16 lds[4][128 * 64];
  const int tid = threadIdx.x;
  const int lane = tid & 63;
  const int w = tid >> 6;
  const int wm = (w >> 1) * 64, wn = (w & 1) * 64;
  const int m0 = blockIdx.y * 128, n0 = blockIdx.x * 128;
  const int l15 = lane & 15, lhi = lane >> 4;

  f32x4 acc[4][4] = {};

  for (int k0 = 0; k0 < EMB; k0 += 64) {
    __syncthreads();
#pragma unroll
    for (int c = 0; c < 4; ++c) {
      int idx = tid + c * 256;
      int row = idx >> 3;
      int col = (idx & 7) * 8;
      size_t gb = (size_t)(n0 + row) * EMB + k0 + col;
      gld16(Bhi + gb, &lds[2][idx * 8]);
      gld16(Blo + gb, &lds[3][idx * 8]);
    }
#pragma unroll
    for (int c = 0; c < 8; ++c) {
      int idx = tid + c * 256;          // 0..2047
      int row = idx >> 4;               // 0..127
      int c4 = (idx & 15) * 4;          // 0..60
      f32x4 xv = *(const f32x4*)&X[(size_t)(m0 + row) * EMB + k0 + c4];
      us4 h4, l4;
#pragma unroll
      for (int e = 0; e < 4; ++e) {
        u16 h = f2bf(xv[e]);
        h4[e] = h;
        l4[e] = f2bf(xv[e] - bf2f(h));
      }
      *(us4*)&lds[0][row * 64 + c4] = h4;
      *(us4*)&lds[1][row * 64 + c4] = l4;
    }
    __syncthreads();
#pragma unroll
    for (int ks = 0; ks < 2; ++ks) {
      int ko = ks * 32 + lhi * 8;
      bf16x8 ah[4], al[4], bh[4], bl[4];
#pragma unroll
      for (int f = 0; f < 4; ++f) {
        int ra = (wm + f * 16 + l15) * 64 + ko;
        int rb = (wn + f * 16 + l15) * 64 + ko;
        ah[f] = *(const bf16x8*)&lds[0][ra];
        al[f] = *(const bf16x8*)&lds[1][ra];
        bh[f] = *(const bf16x8*)&lds[2][rb];
        bl[f] = *(const bf16x8*)&lds[3][rb];
      }
#pragma unroll
      for (int i = 0; i < 4; ++i)
#pragma unroll
        for (int j = 0; j < 4; ++j) {
          acc[i][j] = mfma16(ah[i], bh[j], acc[i][j]);
          acc[i][j] = mfma16(ah[i], bl[j], acc[i][j]);
          acc[i][j] = mfma16(al[i], bh[j], acc[i][j]);
        }
    }
  }
#pragma unroll
  for (int j = 0; j < 4; ++j) {
    int n = n0 + wn + j * 16 + l15;
    float bv = bias2[n];
    int g = n >> 9, jj = n & 511;
#pragma unroll
    for (int i = 0; i < 4; ++i) {
      int mb = m0 + wm + i * 16 + lhi * 4;
      int tloc = mb >> 8, brow = mb & 255;
      int bgrp = brow >> 4, b15 = brow & 15;  // b15 = lhi*4
      f32x4 v = acc[i][j];
      v[0] += bv; v[1] += bv; v[2] += bv; v[3] += bv;
      size_t addr = ((((size_t)tloc * 16 + bgrp) * 4 + g) * 512 + jj) * 16 + b15;
      *(f32x4*)&G2[addr] = v;
    }
  }
}

// ---------- recurrence: 64 blocks = 16 b-groups x 4 j-members, sc1 protocol ----
__global__ __launch_bounds__(256, 1) void k_rnn(
    const u16* __restrict__ WPhi, const u16* __restrict__ WPlo,
    const float* __restrict__ G2,
    u16* __restrict__ hAhi, u16* __restrict__ hAlo,
    u16* __restrict__ hBhi, u16* __restrict__ hBlo,
    float* __restrict__ cSave, unsigned* __restrict__ flags,
    float* __restrict__ out, int t0, int nsteps) {
  extern __shared__ u16 smem[];  // 128KB Waa-lo frags + 8KB reduce @131072
  const int tid = threadIdx.x;
  const int lane = tid & 63;
  const int w = tid >> 6;
  const int l15 = lane & 15, lhi = lane >> 4;
  const int bid = blockIdx.x;
  const int grp = bid & 15;   // b-group
  const int mem = bid >> 4;   // j-slice (128 wide)
  const int jsub = w >> 1, ksub = w & 1;
  const bool owner = (ksub == 0);
  const int b0 = grp * 16;
  const int j0 = mem * 128 + jsub * 64;
  char* smB = (char*)smem;

  // stage Waa-lo frags -> LDS (128KB); Waa-hi frags -> VGPRs (128), pinned
  bf16x8 BH[4][8];
  {
    size_t fb = ((size_t)mem * 4 + w) * 32;
#pragma unroll
    for (int q = 0; q < 32; ++q)
      gld16(WPlo + (fb + q) * 512 + lane * 8,
            smem + ((size_t)w * 32 + q) * 512 + lane * 8);
#pragma unroll
    for (int nf = 0; nf < 4; ++nf)
#pragma unroll
      for (int kf = 0; kf < 8; ++kf) {
        BH[nf][kf] = *(const bf16x8*)(WPhi + (fb + nf * 8 + kf) * 512 + lane * 8);
        asm volatile("" : "+v"(BH[nf][kf]));
      }
  }

  f32x4 cc[4] = {};
  const size_t ctbase = ((size_t)bid * 256 + tid) * 16;
  if (owner && t0 > 0) {
#pragma unroll
    for (int nf = 0; nf < 4; ++nf) cc[nf] = *(const f32x4*)&cSave[ctbase + nf * 4];
  }

  const size_t abase = (size_t)(b0 + l15) * HID + ksub * 256 + lhi * 8;
  unsigned* stepflag = flags + grp * 32;
  __syncthreads();  // Waa-lo staging complete (vmcnt drained by barrier)

  for (int tl = 0; tl < nsteps; ++tl) {
    const int gt = t0 + tl;
    const u16* hHi = (gt & 1) ? hBhi : hAhi;
    const u16* hLo = (gt & 1) ? hBlo : hAlo;
    u16* nHi = (gt & 1) ? hAhi : hBhi;
    u16* nLo = (gt & 1) ? hAlo : hBlo;

    // gate preactivations for this step (h-independent): issue before the wait
    f32x4 gq[4][4];
    if (owner) {
      const float* gp = G2 + ((size_t)tl * 16 + grp) * 4 * 512 * 16;
#pragma unroll
      for (int nf = 0; nf < 4; ++nf)
#pragma unroll
        for (int g = 0; g < 4; ++g)
          gq[nf][g] = *(const f32x4*)(gp + ((size_t)g * 512 + j0 + nf * 16 + l15) * 16 + lhi * 4);
    }

    // wait for h(gt-1) from all members of this group
    if (tl > 0) {
      if (tid == 0) {
        unsigned tgt = 8u * (unsigned)tl;  // 4 members x 2 owner waves per step
        long guard = 0;
        while (flag_poll_dev(stepflag) < tgt) {
          __builtin_amdgcn_s_sleep(1);
          if (++guard > (1L << 22)) break;  // bounded: fail visibly, never hang
        }
      }
      __syncthreads();
    }

    // A-fragments (h hi/lo) for this wave's K-half, via MALL
    bf16x8 aH[8], aL[8];
#pragma unroll
    for (int kf = 0; kf < 8; ++kf) {
      aH[kf] = ldx4_dev(hHi + abase + kf * 32);
      aL[kf] = ldx4_dev(hLo + abase + kf * 32);
    }
    asm volatile("s_waitcnt vmcnt(0)" ::: "memory");
    __builtin_amdgcn_sched_barrier(0);  // rule #18: keep MFMAs below the wait

    // 3-product split-bf16 MFMA (hi*hi + lo*hi + hi*lo)
    f32x4 acc[4];
#pragma unroll
    for (int nf = 0; nf < 4; ++nf) {
      f32x4 p0 = {0.f, 0.f, 0.f, 0.f}, p1 = p0, p2 = p0;
#pragma unroll
      for (int kf = 0; kf < 8; ++kf) {
        bf16x8 bl = *(const bf16x8*)(smB + ((size_t)(w * 32 + nf * 8 + kf)) * 1024 + lane * 16);
        p0 = mfma16(aH[kf], BH[nf][kf], p0);
        p1 = mfma16(aL[kf], BH[nf][kf], p1);
        p2 = mfma16(aH[kf], bl, p2);
      }
      acc[nf] = (p0 + p1) + p2;
    }

    // K-half reduce via LDS (region at byte 128K)
    if (!owner) {
#pragma unroll
      for (int nf = 0; nf < 4; ++nf)
        *(f32x4*)(smB + 131072 + ((size_t)(jsub * 4 + nf) * 64 + lane) * 16) = acc[nf];
    }
    __syncthreads();

    if (owner) {
#pragma unroll
      for (int nf = 0; nf < 4; ++nf) {
        acc[nf] += *(const f32x4*)(smB + 131072 + ((size_t)(jsub * 4 + nf) * 64 + lane) * 16);
#pragma unroll
        for (int r = 0; r < 4; ++r) {
          float z = acc[nf][r];
          float ft = sigmoidf_(gq[nf][0][r] + z);
          float it = sigmoidf_(gq[nf][1][r] + z);
          float ot = sigmoidf_(gq[nf][2][r] + z);
          float cp = tanhf_(gq[nf][3][r] + z);
          float cn = ft * cc[nf][r] + it * cp;
          cc[nf][r] = cn;
          float h = ot * tanhf_(cn);
          int b = b0 + lhi * 4 + r;
          int j = j0 + nf * 16 + l15;
          if (gt == SEQL - 1) {
            out[(size_t)b * HID + j] = h;
          } else {
            u16 hh = f2bf(h), hl = f2bf(h - bf2f(hh));
            st2_dev(nHi + (size_t)b * HID + j, (unsigned)hh);
            st2_dev(nLo + (size_t)b * HID + j, (unsigned)hl);
          }
        }
      }
      if (gt != SEQL - 1) {
        asm volatile("s_waitcnt vmcnt(0)" ::: "memory");  // drain sc1 h stores
        if (lane == 0) flag_add_dev(stepflag);            // release
      }
    }
  }

  if (owner && t0 + nsteps < SEQL) {
#pragma unroll
    for (int nf = 0; nf < 4; ++nf) *(f32x4*)&cSave[ctbase + nf * 4] = cc[nf];
  }
}

// ---------- host ----------
extern "C" void kernel_launch(void* const* d_in, const int* in_sizes, int n_in,
                              void* d_out, int out_size, void* d_ws, size_t ws_size,
                              hipStream_t stream) {
  const float* X   = (const float*)d_in[0];
  const float* Wfx = (const float*)d_in[1];
  const float* Wix = (const float*)d_in[2];
  const float* Wox = (const float*)d_in[3];
  const float* Wax = (const float*)d_in[4];
  const float* Waa = (const float*)d_in[5];
  const float* bfp = (const float*)d_in[6];
  const float* bip = (const float*)d_in[7];
  const float* bop = (const float*)d_in[8];
  const float* bap = (const float*)d_in[9];
  float* out = (float*)d_out;

  char* ws = (char*)d_ws;
  size_t off = 0;
  auto take = [&](size_t n) {
    void* p = ws + off;
    off += (n + 255) & ~(size_t)255;
    return p;
  };
  u16* WxHi   = (u16*)take((size_t)NTOT * EMB * 2);      // 1MB
  u16* WxLo   = (u16*)take((size_t)NTOT * EMB * 2);      // 1MB
  u16* WPhi   = (u16*)take((size_t)512 * 512 * 2);       // 512KB
  u16* WPlo   = (u16*)take((size_t)512 * 512 * 2);       // 512KB
  float* bias2 = (float*)take((size_t)NTOT * 4);
  u16* hAhi = (u16*)take((size_t)BATCH * HID * 2);
  u16* hAlo = (u16*)take((size_t)BATCH * HID * 2);
  u16* hBhi = (u16*)take((size_t)BATCH * HID * 2);
  u16* hBlo = (u16*)take((size_t)BATCH * HID * 2);
  float* cSave = (float*)take((size_t)64 * 256 * 16 * 4);  // 1MB
  unsigned* flags = (unsigned*)take(16 * 32 * 4);
  size_t fixed_end = off;

  const size_t perstep = (size_t)BATCH * NTOT * 4;  // 2MB G2 per step
  int C = 0;
  const int cands[] = {512, 256, 128, 64, 32, 16, 8, 4, 2, 1};
  for (int cand : cands)
    if (fixed_end + (size_t)cand * perstep <= ws_size) { C = cand; break; }
  if (C == 0) return;
  float* G2 = (float*)take((size_t)C * perstep);

  (void)hipFuncSetAttribute((const void*)k_rnn,
                            hipFuncAttributeMaxDynamicSharedMemorySize, 139264);

  // one-time prep
  const float* wx[4] = {Wfx, Wix, Wox, Wax};
  for (int g = 0; g < 4; ++g)
    k_split<<<256, 256, 0, stream>>>(wx[g], WxHi + (size_t)g * HID * EMB,
                                     WxLo + (size_t)g * HID * EMB, HID * EMB);
  k_packW<<<128, 256, 0, stream>>>(Waa, WPhi, WPlo);
  k_bias2<<<8, 256, 0, stream>>>(bfp, bip, bop, bap, bias2);
  hipMemsetAsync(hAhi, 0, (size_t)BATCH * HID * 2 * 2, stream);  // hA hi+lo = 0

  const int nch = SEQL / C;
  for (int ch = 0; ch < nch; ++ch) {
    int t0 = ch * C;
    hipMemsetAsync(flags, 0, 16 * 32 * 4, stream);
    dim3 gg(NTOT / 128, C * 2);
    k_gemm<<<gg, 256, 0, stream>>>(X + (size_t)t0 * BATCH * EMB, WxHi, WxLo,
                                   bias2, G2);
    k_rnn<<<64, 256, 139264, stream>>>(WPhi, WPlo, G2, hAhi, hAlo, hBhi, hBlo,
                                       cSave, flags, out, t0, C);
  }
}